// Round 11
// baseline (617.019 us; speedup 1.0000x reference)
//
#include <hip/hip_runtime.h>
#include <hip/hip_bf16.h>
#include <math.h>

// DockPointNet fused, round 11: LDS diet on edge kernel.
// R10 learning: launch_bounds min-waves doesn't raise residency; LDS (52 KB)
// capped edge at 3 blocks/CU. Fix: st staging buffer (33 KB) is only live
// after hbuf (18 KB) is dead -> overlay st onto hbuf and reduce in two
// 64-feature chunks, holding normalized h2 as 32 packed-bf16 uints in regs
// across the barrier. LDS 53 -> ~20 KB -> VGPR-capped ~4-5 blocks/CU.
// Also: wprep merged into hist launch.

#define LN_EPS 1e-5f
#define EPB 128
#define SM 72     // hbuf row stride in shorts (18432 B total)
#define SC 130    // chunk staging row stride in shorts (64*130=8320 <= 128*72)
#define AS 132    // node a_bf row stride in shorts

typedef __attribute__((ext_vector_type(8))) short bf16x8;
typedef __attribute__((ext_vector_type(4))) float floatx4;
typedef __attribute__((ext_vector_type(4))) short s4v;

__device__ __forceinline__ unsigned ord(float f) {
    int i = __float_as_int(f);
    return (i >= 0) ? ((unsigned)i | 0x80000000u) : ~((unsigned)i);
}
__device__ __forceinline__ float unord(unsigned u) {
    int i = (u & 0x80000000u) ? (int)(u & 0x7fffffffu) : ~(int)u;
    return __int_as_float(i);
}
__device__ __forceinline__ unsigned short f2b(float f) {   // RNE f32->bf16
    unsigned u = __float_as_uint(f);
    return (unsigned short)((u + 0x7FFFu + ((u >> 16) & 1u)) >> 16);
}
__device__ __forceinline__ float b2f(unsigned short h) {
    return __uint_as_float((unsigned)h << 16);
}
__device__ __forceinline__ unsigned f2b2(float lo, float hi) {  // packed pair
    union { __hip_bfloat162 h2; unsigned u; } c;
    c.h2 = __float22bfloat162_rn(make_float2(lo, hi));
    return c.u;
}
__device__ __forceinline__ float b2f_lo(unsigned w) { return __uint_as_float(w << 16); }
__device__ __forceinline__ float b2f_hi(unsigned w) { return __uint_as_float(w & 0xFFFF0000u); }

// ---------------- hist (+wprep piggyback blocks) ----------------
__global__ void hist_wprep_kernel(const int* __restrict__ ei, unsigned* __restrict__ deg, int E,
                                  int nbHist,
                                  const float* __restrict__ W1, const float* __restrict__ W2,
                                  const float* __restrict__ Wg,
                                  unsigned short* __restrict__ W1p, unsigned short* __restrict__ W2p,
                                  unsigned short* __restrict__ Wgp)
{
    if ((int)blockIdx.x >= nbHist) {
        // weight prepack role: 16 blocks
        int gt = ((int)blockIdx.x - nbHist) * 256 + threadIdx.x;
        int gs = 16 * 256;
        for (int fl = gt; fl < 8 * 64; fl += gs) {
            int fi = fl >> 6, l = fl & 63;
            int s = fi >> 2, nt = fi & 3;
            int n = nt * 16 + (l & 15);
            int kb = s * 32 + ((l >> 4) << 3);
            #pragma unroll
            for (int j = 0; j < 8; ++j) {
                int k = kb + j;
                W1p[fl * 8 + j] = f2b((k < 47) ? W1[k * 64 + n] : 0.f);
            }
        }
        for (int fl = gt; fl < 16 * 64; fl += gs) {
            int fi = fl >> 6, l = fl & 63;
            int s = fi >> 3, nt = fi & 7;
            int n = nt * 16 + (l & 15);
            int kb = s * 32 + ((l >> 4) << 3);
            #pragma unroll
            for (int j = 0; j < 8; ++j)
                W2p[fl * 8 + j] = f2b(W2[(kb + j) * 128 + n]);
        }
        for (int fl = gt; fl < 64 * 64; fl += gs) {
            int fi = fl >> 6, l = fl & 63;
            int s = fi >> 4, nt = fi & 15;
            int n = nt * 16 + (l & 15);
            int kb = s * 32 + ((l >> 4) << 3);
            #pragma unroll
            for (int j = 0; j < 8; ++j)
                Wgp[fl * 8 + j] = f2b(Wg[(size_t)(kb + j) * 256 + n]);
        }
        return;
    }
    int b4 = (blockIdx.x * 256 + threadIdx.x) * 4;
    if (b4 + 3 < E) {
        int4 d4 = *(const int4*)(ei + E + b4);
        atomicAdd(&deg[d4.x], 1u);
        atomicAdd(&deg[d4.y], 1u);
        atomicAdd(&deg[d4.z], 1u);
        atomicAdd(&deg[d4.w], 1u);
    } else {
        for (int i = 0; i < 4; ++i)
            if (b4 + i < E) atomicAdd(&deg[ei[E + b4 + i]], 1u);
    }
}

__global__ void scan1(const unsigned* __restrict__ deg, unsigned* __restrict__ part, int N) {
    __shared__ unsigned s[256];
    int i = blockIdx.x * 256 + threadIdx.x;
    s[threadIdx.x] = (i < N) ? deg[i] : 0u;
    __syncthreads();
    for (int st = 128; st > 0; st >>= 1) {
        if (threadIdx.x < st) s[threadIdx.x] += s[threadIdx.x + st];
        __syncthreads();
    }
    if (threadIdx.x == 0) part[blockIdx.x] = s[0];
}

__global__ void scan2(unsigned* __restrict__ part, int nb) {
    __shared__ unsigned s[256];
    int t = threadIdx.x;
    unsigned v = (t < nb) ? part[t] : 0u;
    s[t] = v;
    __syncthreads();
    for (int st = 1; st < 256; st <<= 1) {
        unsigned add = (t >= st) ? s[t - st] : 0u;
        __syncthreads();
        s[t] += add;
        __syncthreads();
    }
    if (t < nb) part[t] = s[t] - v;   // exclusive
}

__global__ void scan3(const unsigned* __restrict__ deg, const unsigned* __restrict__ part,
                      unsigned* __restrict__ off, int N) {
    __shared__ unsigned s[256];
    int i = blockIdx.x * 256 + threadIdx.x, t = threadIdx.x;
    unsigned v = (i < N) ? deg[i] : 0u;
    s[t] = v;
    __syncthreads();
    for (int st = 1; st < 256; st <<= 1) {
        unsigned add = (t >= st) ? s[t - st] : 0u;
        __syncthreads();
        s[t] += add;
        __syncthreads();
    }
    if (i < N) off[i] = part[blockIdx.x] + s[t] - v;   // exclusive
}

__global__ void scatter_kernel(const int* __restrict__ ei, unsigned* __restrict__ cursor,
                               uint2* __restrict__ pd, int E) {
    int b4 = (blockIdx.x * 256 + threadIdx.x) * 4;
    if (b4 + 3 < E) {
        int4 d4 = *(const int4*)(ei + E + b4);
        pd[atomicAdd(&cursor[d4.x], 1u)] = make_uint2((unsigned)(b4 + 0), (unsigned)d4.x);
        pd[atomicAdd(&cursor[d4.y], 1u)] = make_uint2((unsigned)(b4 + 1), (unsigned)d4.y);
        pd[atomicAdd(&cursor[d4.z], 1u)] = make_uint2((unsigned)(b4 + 2), (unsigned)d4.z);
        pd[atomicAdd(&cursor[d4.w], 1u)] = make_uint2((unsigned)(b4 + 3), (unsigned)d4.w);
    } else {
        for (int i = 0; i < 4; ++i)
            if (b4 + i < E) {
                int d = ei[E + b4 + i];
                pd[atomicAdd(&cursor[d], 1u)] = make_uint2((unsigned)(b4 + i), (unsigned)d);
            }
    }
}

// ---------------- fused edge MLP (MFMA) + segmented max ----------------
__global__ __launch_bounds__(256, 4)
void edge_kernel(const float* __restrict__ x,
                 const float* __restrict__ pos,
                 const float* __restrict__ nrm,
                 const float* __restrict__ ea,
                 const int* __restrict__ ei,
                 const uint2* __restrict__ pd,
                 const unsigned short* __restrict__ W1p, const float* __restrict__ b1,
                 const float* __restrict__ g1, const float* __restrict__ be1,
                 const unsigned short* __restrict__ W2p, const float* __restrict__ b2,
                 const float* __restrict__ g2, const float* __restrict__ be2,
                 unsigned* __restrict__ agg, int E)
{
    __shared__ unsigned short hbuf[EPB * SM];   // msg -> h1n -> (overlaid) staging
    __shared__ int dloc[EPB];
    __shared__ short rstart[EPB], rend[EPB];
    __shared__ unsigned long long wmask[2];
    __shared__ int dprev_s, dnext_s;
    unsigned short* stc = hbuf;                  // chunk staging overlays hbuf

    const int tid  = threadIdx.x;
    const int lane = tid & 63;
    const int half = tid >> 7;
    const int el   = tid & 127;
    const int base = blockIdx.x * EPB;
    const int p    = base + el;
    const bool valid = p < E;
    const int nvalid = (E - base < EPB) ? (E - base) : EPB;

    int dst = 0, src = 0, e = 0;
    if (valid) {
        uint2 pv = pd[p];
        e   = (int)pv.x;
        dst = (int)pv.y;
        src = ei[e];
    }
    if (half == 0) dloc[el] = valid ? dst : -1;
    if (tid == 0)
        dprev_s = (blockIdx.x == 0) ? -1 : (int)pd[(size_t)base - 1].y;
    if (tid == 1)
        dnext_s = (base + EPB < E) ? (int)pd[base + EPB].y : -1;

    if (valid) {
        unsigned short* row = &hbuf[el * SM];
        if (half == 0) {
            const float4* xp = (const float4*)(x + (size_t)src * 32);
            #pragma unroll
            for (int q = 0; q < 4; ++q) {
                float4 v = xp[q];
                *(uint2*)&row[4 * q] = make_uint2(f2b2(v.x, v.y), f2b2(v.z, v.w));
            }
            float pix = pos[3*dst+0], piy = pos[3*dst+1], piz = pos[3*dst+2];
            float pjx = pos[3*src+0], pjy = pos[3*src+1], pjz = pos[3*src+2];
            float dx = pjx - pix, dy = pjy - piy, dz = pjz - piz;
            float nix = nrm[3*dst+0], niy = nrm[3*dst+1], niz = nrm[3*dst+2];
            float njx = nrm[3*src+0], njy = nrm[3*src+1], njz = nrm[3*src+2];
            row[32] = f2b(sqrtf(dx*dx + dy*dy + dz*dz) * 0.125f);
            float cx, cy, cz, c2, d, den, inv, sn, cs;
            cx = niy*dz - niz*dy; cy = niz*dx - nix*dz; cz = nix*dy - niy*dx;
            c2 = cx*cx + cy*cy + cz*cz;  d = nix*dx + niy*dy + niz*dz;
            den = c2 + d*d;
            if (den > 0.f) { inv = rsqrtf(den); sn = sqrtf(c2)*inv; cs = d*inv; }
            else           { sn = 0.f; cs = 1.f; }   // atan2(0,0)=0
            row[33] = f2b(sn); row[34] = f2b(cs);
            cx = njy*dz - njz*dy; cy = njz*dx - njx*dz; cz = njx*dy - njy*dx;
            c2 = cx*cx + cy*cy + cz*cz;  d = njx*dx + njy*dy + njz*dz;
            den = c2 + d*d;
            if (den > 0.f) { inv = rsqrtf(den); sn = sqrtf(c2)*inv; cs = d*inv; }
            else           { sn = 0.f; cs = 1.f; }
            row[35] = f2b(sn); row[36] = f2b(cs);
            cx = niy*njz - niz*njy; cy = niz*njx - nix*njz; cz = nix*njy - niy*njx;
            c2 = cx*cx + cy*cy + cz*cz;  d = nix*njx + niy*njy + niz*njz;
            den = c2 + d*d;
            if (den > 0.f) { inv = rsqrtf(den); sn = sqrtf(c2)*inv; cs = d*inv; }
            else           { sn = 0.f; cs = 1.f; }
            row[37] = f2b(sn); row[38] = f2b(cs);
        } else {
            const float4* xp = (const float4*)(x + (size_t)src * 32) + 4;
            #pragma unroll
            for (int q = 0; q < 4; ++q) {
                float4 v = xp[q];
                *(uint2*)&row[16 + 4 * q] = make_uint2(f2b2(v.x, v.y), f2b2(v.z, v.w));
            }
            const float4* ep = (const float4*)(ea + (size_t)e * 8);
            float4 a0 = ep[0], a1 = ep[1];
            row[39] = f2b(a0.x);
            *(uint2*)&row[40] = make_uint2(f2b2(a0.y, a0.z), f2b2(a0.w, a1.x));
            *(uint2*)&row[44] = make_uint2(f2b2(a1.y, a1.z), f2b2(a1.w, 0.f));
            uint2 z = make_uint2(0u, 0u);
            *(uint2*)&row[48] = z; *(uint2*)&row[52] = z;
            *(uint2*)&row[56] = z; *(uint2*)&row[60] = z;
        }
    }
    __syncthreads();   // B1: msg + dloc ready

    bool is_start = false, is_end = false;
    if (tid < 128) {
        int dt = dloc[tid];
        bool isv = tid < nvalid;
        is_start = isv && (tid == 0 || dloc[tid - 1] != dt);
        is_end   = isv && (tid == nvalid - 1 || dloc[tid + 1] != dt);
    }
    {
        unsigned long long mb = __ballot(is_start);
        if ((tid >> 6) < 2 && lane == 0) wmask[tid >> 6] = mb;
    }
    __syncthreads();   // B2: wmask visible
    int nr;
    {
        unsigned long long m0 = wmask[0], m1 = wmask[1];
        nr = __popcll(m0) + __popcll(m1);
        if (tid < 128) {
            int widr = tid >> 6;
            int rid = (widr ? __popcll(m0) : 0)
                    + __popcll((widr ? m1 : m0) & ((1ull << lane) - 1ull));
            if (is_start) rstart[rid] = (short)tid;
            if (is_end)   rend[is_start ? rid : rid - 1] = (short)tid;
        }
    }

    const int wid  = __builtin_amdgcn_readfirstlane(tid >> 6);
    const int quad = lane >> 4, col = lane & 15;
    const int mb0  = wid * 32;

    // GEMM1: 47(->64) -> 64  (wave-private rows, no barriers)
    {
        bf16x8 w1f[8];
        const bf16x8* W1v = (const bf16x8*)W1p;
        #pragma unroll
        for (int i = 0; i < 8; ++i) w1f[i] = W1v[i * 64 + lane];
        float b1v[4], g1v[4], e1v[4];
        #pragma unroll
        for (int nt = 0; nt < 4; ++nt) {
            b1v[nt] = b1[nt*16 + col]; g1v[nt] = g1[nt*16 + col]; e1v[nt] = be1[nt*16 + col];
        }
        #pragma unroll
        for (int t = 0; t < 2; ++t) {
            const int mb = mb0 + t * 16;
            floatx4 acc[4] = {{0,0,0,0},{0,0,0,0},{0,0,0,0},{0,0,0,0}};
            #pragma unroll
            for (int s = 0; s < 2; ++s) {
                const unsigned short* ap = &hbuf[(mb + col) * SM + s*32 + quad*8];
                union { s4v h[2]; bf16x8 v; } u;
                u.h[0] = *(const s4v*)ap; u.h[1] = *(const s4v*)(ap + 4);
                #pragma unroll
                for (int nt = 0; nt < 4; ++nt)
                    acc[nt] = __builtin_amdgcn_mfma_f32_16x16x32_bf16(u.v, w1f[s*4+nt], acc[nt], 0, 0, 0);
            }
            float ps[4] = {0,0,0,0}, p2[4] = {0,0,0,0};
            #pragma unroll
            for (int nt = 0; nt < 4; ++nt)
                #pragma unroll
                for (int r = 0; r < 4; ++r) {
                    float v = fmaxf(acc[nt][r] + b1v[nt], 0.f);
                    acc[nt][r] = v; ps[r] += v; p2[r] += v * v;
                }
            #pragma unroll
            for (int r = 0; r < 4; ++r) {
                #pragma unroll
                for (int m = 1; m < 16; m <<= 1) {
                    ps[r] += __shfl_xor(ps[r], m);
                    p2[r] += __shfl_xor(p2[r], m);
                }
            }
            float mu[4], rs[4];
            #pragma unroll
            for (int r = 0; r < 4; ++r) {
                mu[r] = ps[r] * (1.f/64.f);
                float var = fmaxf(p2[r] * (1.f/64.f) - mu[r]*mu[r], 0.f);
                rs[r] = rsqrtf(var + LN_EPS);
            }
            #pragma unroll
            for (int nt = 0; nt < 4; ++nt) {
                #pragma unroll
                for (int r = 0; r < 4; r += 2) {
                    float h0 = (acc[nt][r]   - mu[r])   * rs[r]   * g1v[nt] + e1v[nt];
                    float h1 = (acc[nt][r+1] - mu[r+1]) * rs[r+1] * g1v[nt] + e1v[nt];
                    unsigned pk = f2b2(h0, h1);
                    hbuf[(mb + quad*4 + r)   * SM + nt*16 + col] = (unsigned short)pk;
                    hbuf[(mb + quad*4 + r+1) * SM + nt*16 + col] = (unsigned short)(pk >> 16);
                }
            }
        }
    }
    // GEMM2: 64 -> 128; keep normalized result as packed bf16 in regs
    unsigned pk2[2][8][2];   // [tile][nt][pair] -> 32 VGPRs
    {
        bf16x8 w2f[16];
        const bf16x8* W2v = (const bf16x8*)W2p;
        #pragma unroll
        for (int i = 0; i < 16; ++i) w2f[i] = W2v[i * 64 + lane];
        float b2v[8], g2v[8], e2v[8];
        #pragma unroll
        for (int nt = 0; nt < 8; ++nt) {
            b2v[nt] = b2[nt*16 + col]; g2v[nt] = g2[nt*16 + col]; e2v[nt] = be2[nt*16 + col];
        }
        #pragma unroll
        for (int t = 0; t < 2; ++t) {
            const int mb = mb0 + t * 16;
            floatx4 acc[8] = {{0,0,0,0},{0,0,0,0},{0,0,0,0},{0,0,0,0},
                              {0,0,0,0},{0,0,0,0},{0,0,0,0},{0,0,0,0}};
            #pragma unroll
            for (int s = 0; s < 2; ++s) {
                const unsigned short* ap = &hbuf[(mb + col) * SM + s*32 + quad*8];
                union { s4v h[2]; bf16x8 v; } u;
                u.h[0] = *(const s4v*)ap; u.h[1] = *(const s4v*)(ap + 4);
                #pragma unroll
                for (int nt = 0; nt < 8; ++nt)
                    acc[nt] = __builtin_amdgcn_mfma_f32_16x16x32_bf16(u.v, w2f[s*8+nt], acc[nt], 0, 0, 0);
            }
            float ps[4] = {0,0,0,0}, p2[4] = {0,0,0,0};
            #pragma unroll
            for (int nt = 0; nt < 8; ++nt)
                #pragma unroll
                for (int r = 0; r < 4; ++r) {
                    float v = fmaxf(acc[nt][r] + b2v[nt], 0.f);
                    acc[nt][r] = v; ps[r] += v; p2[r] += v * v;
                }
            #pragma unroll
            for (int r = 0; r < 4; ++r) {
                #pragma unroll
                for (int m = 1; m < 16; m <<= 1) {
                    ps[r] += __shfl_xor(ps[r], m);
                    p2[r] += __shfl_xor(p2[r], m);
                }
            }
            float mu[4], rs[4];
            #pragma unroll
            for (int r = 0; r < 4; ++r) {
                mu[r] = ps[r] * (1.f/128.f);
                float var = fmaxf(p2[r] * (1.f/128.f) - mu[r]*mu[r], 0.f);
                rs[r] = rsqrtf(var + LN_EPS);
            }
            #pragma unroll
            for (int nt = 0; nt < 8; ++nt) {
                float h0 = (acc[nt][0] - mu[0]) * rs[0] * g2v[nt] + e2v[nt];
                float h1 = (acc[nt][1] - mu[1]) * rs[1] * g2v[nt] + e2v[nt];
                float h2 = (acc[nt][2] - mu[2]) * rs[2] * g2v[nt] + e2v[nt];
                float h3 = (acc[nt][3] - mu[3]) * rs[3] * g2v[nt] + e2v[nt];
                pk2[t][nt][0] = f2b2(h0, h1);
                pk2[t][nt][1] = f2b2(h2, h3);
            }
        }
    }
    __syncthreads();   // B3: all hbuf reads done; staging may overlay

    // ---- segmented max in two 64-feature chunks (staging overlays hbuf) ----
    #pragma unroll
    for (int ch = 0; ch < 2; ++ch) {
        // stage chunk features: pk2[t][ch*4+j] -> features (ch*4+j)*16+col - ch*64
        #pragma unroll
        for (int t = 0; t < 2; ++t) {
            const int mb = mb0 + t * 16;
            #pragma unroll
            for (int j = 0; j < 4; ++j) {
                int f = j * 16 + col;   // feature within chunk (0..63)
                unsigned* d32 = (unsigned*)&stc[f * SC + mb + quad*4];
                d32[0] = pk2[t][ch*4 + j][0];
                d32[1] = pk2[t][ch*4 + j][1];
            }
        }
        __syncthreads();   // staging visible (and, ch=0, rstart/rend ready)
        {
            const int grp = tid >> 6;        // 0..3
            const int f   = tid & 63;
            const unsigned short* fr = &stc[f * SC];
            const unsigned* fp = (const unsigned*)fr;   // f*SC even -> aligned
            for (int r = grp; r < nr; r += 4) {
                int s0 = rstart[r], en = rend[r];
                int d  = dloc[s0];
                float v0 = -1e30f, v1 = -1e30f;
                int c = s0;
                if (c & 1) { v0 = fmaxf(v0, b2f(fr[c])); ++c; }
                for (; c + 3 <= en; c += 4) {
                    unsigned wa = fp[c >> 1], wb = fp[(c >> 1) + 1];
                    v0 = fmaxf(v0, fmaxf(b2f_lo(wa), b2f_hi(wa)));
                    v1 = fmaxf(v1, fmaxf(b2f_lo(wb), b2f_hi(wb)));
                }
                if (c + 1 <= en) {
                    unsigned wa = fp[c >> 1];
                    v0 = fmaxf(v0, fmaxf(b2f_lo(wa), b2f_hi(wa)));
                    c += 2;
                }
                if (c <= en) v0 = fmaxf(v0, b2f(fr[c]));
                float val = fmaxf(v0, v1);
                bool contPrev = (s0 == 0) && (dprev_s == d);
                bool contNext = (en == nvalid - 1) && (dnext_s == d);
                unsigned enc = ord(val);
                unsigned* ap = agg + (size_t)d * 128 + ch * 64 + f;
                if (contPrev || contNext) atomicMax(ap, enc);
                else                      *ap = enc;
            }
        }
        __syncthreads();   // reduce done before restage
    }
}

// ---------------- node MLP (MFMA) ----------------
__global__ __launch_bounds__(256, 4)
void node_kernel(const unsigned* __restrict__ agg,
                 const unsigned short* __restrict__ Wgp, const float* __restrict__ bg,
                 const float* __restrict__ gg, const float* __restrict__ beg,
                 float* __restrict__ out, int N)
{
    __shared__ unsigned short a_bf[64 * AS];
    const int tid  = threadIdx.x;
    const int base = blockIdx.x * 64;
    const size_t total = (size_t)N * 128;

    #pragma unroll
    for (int i = 0; i < 32; ++i) {
        int idx = tid + i * 256;
        int nl = idx >> 7, k = idx & 127;
        size_t g = (size_t)base * 128 + idx;
        unsigned u = (g < total) ? agg[g] : 0u;
        a_bf[nl * AS + k] = (u == 0u) ? (unsigned short)0 : f2b(unord(u));
    }
    __syncthreads();

    const int lane = tid & 63;
    const int wid  = __builtin_amdgcn_readfirstlane(tid >> 6);
    const int quad = lane >> 4, col = lane & 15;
    const int m0   = wid * 16;

    bf16x8 af[4];
    #pragma unroll
    for (int s = 0; s < 4; ++s) {
        const unsigned short* ap = &a_bf[(m0 + col) * AS + s*32 + quad*8];
        union { s4v h[2]; bf16x8 v; } u;
        u.h[0] = *(const s4v*)ap; u.h[1] = *(const s4v*)(ap + 4);
        af[s] = u.v;
    }

    float accv[16][4];
    float ps[4] = {0,0,0,0}, p2[4] = {0,0,0,0};
    const bf16x8* Wv = (const bf16x8*)Wgp;
    #pragma unroll
    for (int nt = 0; nt < 16; ++nt) {
        floatx4 acc = {0, 0, 0, 0};
        #pragma unroll
        for (int s = 0; s < 4; ++s)
            acc = __builtin_amdgcn_mfma_f32_16x16x32_bf16(af[s], Wv[(s*16 + nt)*64 + lane], acc, 0, 0, 0);
        float b = bg[nt*16 + col];
        #pragma unroll
        for (int r = 0; r < 4; ++r) {
            float v = fmaxf(acc[r] + b, 0.f);
            accv[nt][r] = v; ps[r] += v; p2[r] += v * v;
        }
    }
    #pragma unroll
    for (int r = 0; r < 4; ++r) {
        #pragma unroll
        for (int m = 1; m < 16; m <<= 1) {
            ps[r] += __shfl_xor(ps[r], m);
            p2[r] += __shfl_xor(p2[r], m);
        }
    }
    float mu[4], rs[4];
    #pragma unroll
    for (int r = 0; r < 4; ++r) {
        mu[r] = ps[r] * (1.f/256.f);
        float var = fmaxf(p2[r] * (1.f/256.f) - mu[r]*mu[r], 0.f);
        rs[r] = rsqrtf(var + LN_EPS);
    }
    #pragma unroll
    for (int nt = 0; nt < 16; ++nt) {
        float g = gg[nt*16 + col], be = beg[nt*16 + col];
        #pragma unroll
        for (int r = 0; r < 4; ++r) {
            int node = base + m0 + quad*4 + r;
            if (node < N)
                out[(size_t)node * 256 + nt*16 + col] = (accv[nt][r] - mu[r]) * rs[r] * g + be;
        }
    }
}

extern "C" void kernel_launch(void* const* d_in, const int* in_sizes, int n_in,
                              void* d_out, int out_size, void* d_ws, size_t ws_size,
                              hipStream_t stream) {
    const float* x         = (const float*)d_in[0];
    const float* pos       = (const float*)d_in[1];
    const float* nrm       = (const float*)d_in[2];
    const float* edge_attr = (const float*)d_in[3];
    const int*   ei        = (const int*)d_in[4];
    const float* W1  = (const float*)d_in[5];
    const float* b1  = (const float*)d_in[6];
    const float* g1  = (const float*)d_in[7];
    const float* be1 = (const float*)d_in[8];
    const float* W2  = (const float*)d_in[9];
    const float* b2  = (const float*)d_in[10];
    const float* g2  = (const float*)d_in[11];
    const float* be2 = (const float*)d_in[12];
    const float* Wg  = (const float*)d_in[13];
    const float* bg  = (const float*)d_in[14];
    const float* gg  = (const float*)d_in[15];
    const float* beg = (const float*)d_in[16];

    const int E = in_sizes[3] / 8;    // edge_attr is [E,8]
    const int N = in_sizes[0] / 32;   // x is [N,32]

    char* ws = (char*)d_ws;
    unsigned* agg  = (unsigned*)ws;                   ws += (size_t)N * 128 * 4;
    unsigned* deg  = (unsigned*)ws;                   ws += (size_t)N * 4;
    unsigned* off  = (unsigned*)ws;                   ws += (size_t)N * 4;
    unsigned* part = (unsigned*)ws;                   ws += 256 * 4;
    uint2*    pd   = (uint2*)ws;                      ws += (size_t)E * 8;
    unsigned short* W1p = (unsigned short*)ws;        ws += 8 * 64 * 8 * 2;
    unsigned short* W2p = (unsigned short*)ws;        ws += 16 * 64 * 8 * 2;
    unsigned short* Wgp = (unsigned short*)ws;        ws += 64 * 64 * 8 * 2;

    hipMemsetAsync(agg, 0, (size_t)N * 128 * 4, stream);
    hipMemsetAsync(deg, 0, (size_t)N * 4, stream);

    const int nbN = (N + 255) / 256;
    const int nbE4 = (E + 1023) / 1024;
    hipLaunchKernelGGL(hist_wprep_kernel, dim3(nbE4 + 16), dim3(256), 0, stream,
                       ei, deg, E, nbE4, W1, W2, Wg, W1p, W2p, Wgp);
    hipLaunchKernelGGL(scan1, dim3(nbN), dim3(256), 0, stream, deg, part, N);
    hipLaunchKernelGGL(scan2, dim3(1), dim3(256), 0, stream, part, nbN);
    hipLaunchKernelGGL(scan3, dim3(nbN), dim3(256), 0, stream, deg, part, off, N);
    hipLaunchKernelGGL(scatter_kernel, dim3(nbE4), dim3(256), 0, stream, ei, off, pd, E);

    hipLaunchKernelGGL(edge_kernel, dim3((E + EPB - 1) / EPB), dim3(256), 0, stream,
                       x, pos, nrm, edge_attr, ei, pd,
                       W1p, b1, g1, be1, W2p, b2, g2, be2, agg, E);

    hipLaunchKernelGGL(node_kernel, dim3((N + 63) / 64), dim3(256), 0, stream,
                       agg, Wgp, bg, gg, beg, (float*)d_out, N);
}